// Round 7
// baseline (137.471 us; speedup 1.0000x reference)
//
#include <hip/hip_runtime.h>
#include <float.h>

#define NROWS  50000
#define NF     32
#define NTREES 300
#define NINT   63
#define NLEAF  64
#define LRATE  0.1f
#define RPB    256     // rows per block == threads per block
#define TPG    30      // trees per group (multiple of 6 for ILP-6, 3 classes)
#define TG     10      // tree groups; TPG*TG == NTREES
#define SORTN  1024    // per-feature padded threshold-list capacity

// ---------- P0: init gcnt=0, sorted=FLT_MAX ----------
__global__ __launch_bounds__(256) void gb_init_ws(int* __restrict__ gcnt,
                                                  float* __restrict__ sorted_all) {
    int i = blockIdx.x * 256 + threadIdx.x;
    if (i < NF) gcnt[i] = 0;
    if (i < NF * SORTN) sorted_all[i] = FLT_MAX;
}

// ---------- P1: append (thr, node_id) to per-feature lists ----------
// Append order is nondeterministic, but all consumers are order-independent
// (strict-rank counts + bit-identical duplicate placement) -> deterministic output.
__global__ __launch_bounds__(256) void gb_scatter(const int* __restrict__ feat,
                                                  const float* __restrict__ thr,
                                                  int* __restrict__ gcnt,
                                                  int2* __restrict__ glist) {
    int j = blockIdx.x * 256 + threadIdx.x;
    if (j >= NTREES * NINT) return;
    int f = feat[j];
    int p = atomicAdd(&gcnt[f], 1);
    glist[f * SORTN + p] = make_int2(__float_as_int(thr[j]), j);
}

// ---------- P2: per-feature strict ranks by counting; build sorted + pack ----------
// block f stages its ~590-entry list in LDS; inner loop address is uniform
// across lanes -> LDS broadcast (conflict-free).
__global__ __launch_bounds__(256) void gb_rank_nodes(const int* __restrict__ gcnt,
                                                     const int2* __restrict__ glist,
                                                     float* __restrict__ sorted_all,
                                                     unsigned* __restrict__ pack) {
    __shared__ int2 sl[SORTN];
    const int f = blockIdx.x, t = threadIdx.x;
    const int n = gcnt[f];
    for (int i = t; i < n; i += 256) sl[i] = glist[f * SORTN + i];
    __syncthreads();
    for (int k = t; k < n; k += 256) {
        float tv = __int_as_float(sl[k].x);
        int   j  = sl[k].y;
        int lt = 0, tie = 0;
        for (int i = 0; i < n; ++i) {
            float si = __int_as_float(sl[i].x);
            lt  += (si < tv) ? 1 : 0;
            tie += ((si == tv) && (i < k)) ? 1 : 0;
        }
        sorted_all[f * SORTN + (lt + tie)] = tv;          // bijective scatter
        int tree = j / NINT, node = j - tree * NINT;
        pack[tree * 64 + node] = ((unsigned)lt << 5) | (unsigned)f;
    }
}

// ---------- P3: rank every x value (10-step branchless lower_bound); init out ----------
__global__ __launch_bounds__(256) void gb_rank_rows(const float* __restrict__ x,
                                                    const float* __restrict__ sorted_all,
                                                    const float* __restrict__ initp,
                                                    unsigned short* __restrict__ xr,
                                                    float* __restrict__ out) {
    __shared__ float s[SORTN];
    const int f = blockIdx.y;
    const int t = threadIdx.x;
    for (int i = t; i < SORTN; i += 256) s[i] = sorted_all[f * SORTN + i];
    __syncthreads();
    int row = blockIdx.x * 256 + t;
    if (row < NROWS) {
        float xv = x[(size_t)row * NF + f];
        int idx = 0;                           // L(x) = #{t' < x}; FLT_MAX pad
        #pragma unroll
        for (int st = SORTN / 2; st >= 1; st >>= 1) {
            int c = idx + st;
            if (s[c - 1] < xv) idx = c;
        }
        xr[(size_t)f * NROWS + row] = (unsigned short)idx;
        if (f == 0) {
            out[row * 3 + 0] = initp[0];
            out[row * 3 + 1] = initp[1];
            out[row * 3 + 2] = initp[2];
        }
    }
}

// ---------- main: integer-rank tree walk (x > t  <=>  L(x) > lt, exact) ----------
__global__ __launch_bounds__(RPB, 6) void gb_forest(
    const unsigned short* __restrict__ xr,    // [NF][NROWS] ranks
    const unsigned*       __restrict__ pack,  // [NTREES][64] packed nodes
    const float*          __restrict__ leaves,// [NTREES][64]
    float*                __restrict__ out)   // [NROWS][3]
{
    // 16384 + 7680 = 24064 B -> 6 blocks/CU (24 waves/CU)
    __shared__ unsigned short xs[NF][RPB];
    __shared__ unsigned nodes[TPG][64];

    const int tid  = threadIdx.x;
    const int r0   = blockIdx.x * RPB;
    const int m0   = blockIdx.y * TPG;
    const int grow = r0 + tid;
    const int gr   = grow < NROWS ? grow : NROWS - 1;

    #pragma unroll
    for (int f = 0; f < NF; ++f) xs[f][tid] = xr[(size_t)f * NROWS + gr];
    for (int i = tid; i < TPG * 64; i += RPB)
        ((unsigned*)nodes)[i] = pack[m0 * 64 + i];
    __syncthreads();

    float acc0 = 0.f, acc1 = 0.f, acc2 = 0.f;
    #pragma unroll
    for (int g = 0; g < TPG; g += 6) {
        unsigned jj[6] = {0, 0, 0, 0, 0, 0};
        #pragma unroll
        for (int d = 0; d < 6; ++d) {
            #pragma unroll
            for (int c = 0; c < 6; ++c) {
                unsigned nd = nodes[g + c][jj[c]];        // ds_read_b32 gather
                unsigned xv = xs[nd & 31u][tid];          // ds_read_u16, conflict-free
                jj[c] = 2u * jj[c] + 1u + (xv > (nd >> 5) ? 1u : 0u);
            }
        }
        #pragma unroll
        for (int c = 0; c < 6; ++c) {
            float lv = leaves[(size_t)(m0 + g + c) * NLEAF + (jj[c] - NINT)];
            if (c % 3 == 0)      acc0 += lv;
            else if (c % 3 == 1) acc1 += lv;
            else                 acc2 += lv;
        }
    }

    if (grow < NROWS) {
        atomicAdd(&out[grow * 3 + 0], LRATE * acc0);
        atomicAdd(&out[grow * 3 + 1], LRATE * acc1);
        atomicAdd(&out[grow * 3 + 2], LRATE * acc2);
    }
}

// ---------- fallback (ws too small): round-2 style f32 kernel ----------
__global__ void gb_init_out(const float* __restrict__ initp,
                            float* __restrict__ out, int n) {
    int i = blockIdx.x * blockDim.x + threadIdx.x;
    if (i < n) out[i] = initp[i % 3];
}

__global__ __launch_bounds__(RPB, 4) void gb_forest_fb(
    const float* __restrict__ x, const int* __restrict__ feat,
    const float* __restrict__ thr, const float* __restrict__ leaves,
    float* __restrict__ out) {
    __shared__ float xsf[NF][RPB];
    __shared__ int2  nodesf[12][64];
    const int tid = threadIdx.x;
    const int r0 = blockIdx.x * RPB;
    const int m0 = blockIdx.y * 12;
    const int grow = r0 + tid;
    {
        const float4* xrp = (const float4*)x + (size_t)(grow < NROWS ? grow : NROWS - 1) * (NF / 4);
        float4 v[8];
        #pragma unroll
        for (int k = 0; k < 8; ++k) v[k] = xrp[k];
        #pragma unroll
        for (int k = 0; k < 8; ++k) {
            xsf[k*4+0][tid] = v[k].x; xsf[k*4+1][tid] = v[k].y;
            xsf[k*4+2][tid] = v[k].z; xsf[k*4+3][tid] = v[k].w;
        }
    }
    for (int i = tid; i < 12 * NINT; i += RPB) {
        int tl = i / NINT, nd = i - tl * NINT;
        int gi = (m0 + tl) * NINT + nd;
        nodesf[tl][nd] = make_int2(feat[gi], __float_as_int(thr[gi]));
    }
    __syncthreads();
    float acc0 = 0.f, acc1 = 0.f, acc2 = 0.f;
    for (int it = 0; it < 12; it += 6) {
        int idx[6] = {0,0,0,0,0,0};
        #pragma unroll
        for (int d = 0; d < 6; ++d) {
            #pragma unroll
            for (int j = 0; j < 6; ++j) {
                int2 nd = nodesf[it + j][idx[j]];
                idx[j] = 2*idx[j] + 1 + (int)(xsf[nd.x][tid] > __int_as_float(nd.y));
            }
        }
        #pragma unroll
        for (int j = 0; j < 6; ++j) {
            float lv = leaves[(m0 + it + j) * NLEAF + (idx[j] - NINT)];
            if (j % 3 == 0) acc0 += lv; else if (j % 3 == 1) acc1 += lv; else acc2 += lv;
        }
    }
    if (grow < NROWS) {
        atomicAdd(&out[grow*3+0], LRATE*acc0);
        atomicAdd(&out[grow*3+1], LRATE*acc1);
        atomicAdd(&out[grow*3+2], LRATE*acc2);
    }
}

extern "C" void kernel_launch(void* const* d_in, const int* in_sizes, int n_in,
                              void* d_out, int out_size, void* d_ws, size_t ws_size,
                              hipStream_t stream) {
    const float* x      = (const float*)d_in[0];
    const int*   feat   = (const int*)d_in[1];
    const float* thr    = (const float*)d_in[2];
    const float* leaves = (const float*)d_in[3];
    const float* initp  = (const float*)d_in[4];
    float* out = (float*)d_out;

    // ws layout (aliased):
    //   [0, 3200000)        xr u16[NF][NROWS]     (written by P3, read by forest)
    //     [0,128)           gcnt int[32]          (P0/P1/P2 only -- dead before P3)
    //     [128, 262272)     glist int2[NF][SORTN] (P1/P2 only -- dead before P3)
    //   [3200000, 3331072)  sorted f32[NF][SORTN]
    //   [3331072, 3407872)  pack u32[NTREES][64]
    const size_t off_sorted = (size_t)NF * NROWS * 2;               // 3,200,000
    const size_t off_pack   = off_sorted + (size_t)NF * SORTN * 4;  // 3,331,072
    const size_t need       = off_pack + (size_t)NTREES * 64 * 4;   // 3,407,872

    if (ws_size >= need) {
        unsigned short* xrbuf  = (unsigned short*)d_ws;
        int*            gcnt   = (int*)d_ws;
        int2*           glist  = (int2*)((char*)d_ws + 128);
        float*          sorted = (float*)((char*)d_ws + off_sorted);
        unsigned*       pack   = (unsigned*)((char*)d_ws + off_pack);

        gb_init_ws<<<(NF * SORTN + 255) / 256, 256, 0, stream>>>(gcnt, sorted);
        gb_scatter<<<(NTREES * NINT + 255) / 256, 256, 0, stream>>>(feat, thr, gcnt, glist);
        gb_rank_nodes<<<NF, 256, 0, stream>>>(gcnt, glist, sorted, pack);
        dim3 g3((NROWS + 255) / 256, NF);
        gb_rank_rows<<<g3, 256, 0, stream>>>(x, sorted, initp, xrbuf, out);
        dim3 grid((NROWS + RPB - 1) / RPB, TG);
        gb_forest<<<grid, RPB, 0, stream>>>(xrbuf, pack, leaves, out);
    } else {
        gb_init_out<<<(out_size + 255) / 256, 256, 0, stream>>>(initp, out, out_size);
        dim3 grid((NROWS + RPB - 1) / RPB, 25);
        gb_forest_fb<<<grid, RPB, 0, stream>>>(x, feat, thr, leaves, out);
    }
}

// Round 8
// 74.517 us; speedup vs baseline: 1.8448x; 1.8448x over previous
//
#include <hip/hip_runtime.h>
#include <float.h>

#define NROWS  50000
#define NF     32
#define NTREES 300
#define NINT   63
#define NLEAF  64
#define NNODES (NTREES * NINT)   // 18900
#define LRATE  0.1f
#define RPB    256
#define TPG    30      // trees per group in forest kernel
#define TG     10      // tree groups; TPG*TG == NTREES
#define SORTN  1024    // per-feature padded threshold-list capacity
#define SLICES 8       // id-slices per feature in prep

// ---------- K1: per-feature collect + ballot-rank -> sorted[] and pack[] ----------
// Block (f, s): compact feature-f matches into LDS (LDS atomic; order
// nondeterministic, but consumers are order-independent counts / canonical
// (key,id)-lex ranks -> deterministic output). Wave-per-target ballot count.
__global__ __launch_bounds__(256) void gb_prep(const int* __restrict__ feat,
                                               const float* __restrict__ thr,
                                               float* __restrict__ sorted_all,
                                               unsigned* __restrict__ pack) {
    __shared__ int2 sl[SORTN];    // full match list (key_bits, id)
    __shared__ int2 tl[SORTN];    // this block's id-slice targets
    __shared__ int cnt, tcnt;
    const int f = blockIdx.x, s = blockIdx.y, t = threadIdx.x;
    const int chunk = (NNODES + SLICES - 1) / SLICES;          // 2363
    const int lo = s * chunk, hi = min(lo + chunk, NNODES);

    if (t == 0) { cnt = 0; tcnt = 0; }
    for (int i = t; i < SORTN; i += 256)
        sl[i] = make_int2(__float_as_int(FLT_MAX), 0x7FFFFFFF);  // pad: never matches
    __syncthreads();

    for (int j = t; j < NNODES; j += 256) {
        if (feat[j] == f) {
            int tb = __float_as_int(thr[j]);
            int p = atomicAdd(&cnt, 1);
            if (p < SORTN) sl[p] = make_int2(tb, j);
            if (j >= lo && j < hi) {
                int q = atomicAdd(&tcnt, 1);
                if (q < SORTN) tl[q] = make_int2(tb, j);
            }
        }
    }
    __syncthreads();

    const int n = min(cnt, SORTN);
    const int m = min(tcnt, SORTN);
    const int lane = t & 63, wid = t >> 6;

    for (int k = wid; k < m; k += 4) {               // wave per target
        const float tv = __int_as_float(tl[k].x);    // uniform within wave
        const int   j  = tl[k].y;
        int c_lt = 0, c_lex = 0;
        #pragma unroll
        for (int c = 0; c < SORTN / 64; ++c) {       // 16 iters cover 1024 slots
            int2 e = sl[c * 64 + lane];
            float si = __int_as_float(e.x);
            bool p_lt  = (si < tv);
            bool p_lex = p_lt || (si == tv && e.y < j);
            c_lt  += (int)__popcll(__ballot(p_lt));
            c_lex += (int)__popcll(__ballot(p_lex));
        }
        if (lane == 0) {
            sorted_all[f * SORTN + c_lex] = tv;      // bijective (lex rank) scatter
            int tree = j / NINT, node = j - tree * NINT;
            pack[tree * 64 + node] = ((unsigned)c_lt << 5) | (unsigned)f;
        }
    }
    if (s == 0) {                                    // pad tail for binary search
        for (int i = n + t; i < SORTN; i += 256)
            sorted_all[f * SORTN + i] = FLT_MAX;
    }
}

// ---------- K2: rank every x value (10-step lower_bound); init out ----------
__global__ __launch_bounds__(256) void gb_rank_rows(const float* __restrict__ x,
                                                    const float* __restrict__ sorted_all,
                                                    const float* __restrict__ initp,
                                                    unsigned short* __restrict__ xr,
                                                    float* __restrict__ out) {
    __shared__ float sarr[SORTN];
    const int f = blockIdx.y;
    const int t = threadIdx.x;
    for (int i = t; i < SORTN; i += 256) sarr[i] = sorted_all[f * SORTN + i];
    __syncthreads();
    int row = blockIdx.x * 256 + t;
    if (row < NROWS) {
        float xv = x[(size_t)row * NF + f];
        int idx = 0;                                  // L(x) = #{t' < x}
        #pragma unroll
        for (int st = SORTN / 2; st >= 1; st >>= 1) {
            int c = idx + st;
            if (sarr[c - 1] < xv) idx = c;
        }
        xr[(size_t)f * NROWS + row] = (unsigned short)idx;
        if (f == 0) {
            out[row * 3 + 0] = initp[0];
            out[row * 3 + 1] = initp[1];
            out[row * 3 + 2] = initp[2];
        }
    }
}

// ---------- K3: integer-rank tree walk (x > t  <=>  L(x) > lt, exact) ----------
__global__ __launch_bounds__(RPB, 6) void gb_forest(
    const unsigned short* __restrict__ xr,    // [NF][NROWS]
    const unsigned*       __restrict__ pack,  // [NTREES][64]
    const float*          __restrict__ leaves,// [NTREES][64]
    float*                __restrict__ out)   // [NROWS][3]
{
    // 16384 + 7680 = 24064 B -> 6 blocks/CU (24 waves/CU)
    __shared__ unsigned short xs[NF][RPB];
    __shared__ unsigned nodes[TPG][64];

    const int tid  = threadIdx.x;
    const int r0   = blockIdx.x * RPB;
    const int m0   = blockIdx.y * TPG;
    const int grow = r0 + tid;
    const int gr   = grow < NROWS ? grow : NROWS - 1;

    #pragma unroll
    for (int f = 0; f < NF; ++f) xs[f][tid] = xr[(size_t)f * NROWS + gr];
    for (int i = tid; i < TPG * 64; i += RPB)
        ((unsigned*)nodes)[i] = pack[m0 * 64 + i];
    __syncthreads();

    float acc0 = 0.f, acc1 = 0.f, acc2 = 0.f;
    #pragma unroll
    for (int g = 0; g < TPG; g += 6) {
        unsigned jj[6] = {0, 0, 0, 0, 0, 0};
        #pragma unroll
        for (int d = 0; d < 6; ++d) {
            #pragma unroll
            for (int c = 0; c < 6; ++c) {
                unsigned nd = nodes[g + c][jj[c]];        // ds_read_b32 gather
                unsigned xv = xs[nd & 31u][tid];          // ds_read_u16, conflict-free
                jj[c] = 2u * jj[c] + 1u + (xv > (nd >> 5) ? 1u : 0u);
            }
        }
        #pragma unroll
        for (int c = 0; c < 6; ++c) {
            float lv = leaves[(size_t)(m0 + g + c) * NLEAF + (jj[c] - NINT)];
            if (c % 3 == 0)      acc0 += lv;
            else if (c % 3 == 1) acc1 += lv;
            else                 acc2 += lv;
        }
    }

    if (grow < NROWS) {
        atomicAdd(&out[grow * 3 + 0], LRATE * acc0);
        atomicAdd(&out[grow * 3 + 1], LRATE * acc1);
        atomicAdd(&out[grow * 3 + 2], LRATE * acc2);
    }
}

// ---------- fallback (ws too small): round-2 style f32 kernel ----------
__global__ void gb_init_out(const float* __restrict__ initp,
                            float* __restrict__ out, int n) {
    int i = blockIdx.x * blockDim.x + threadIdx.x;
    if (i < n) out[i] = initp[i % 3];
}

__global__ __launch_bounds__(RPB, 4) void gb_forest_fb(
    const float* __restrict__ x, const int* __restrict__ feat,
    const float* __restrict__ thr, const float* __restrict__ leaves,
    float* __restrict__ out) {
    __shared__ float xsf[NF][RPB];
    __shared__ int2  nodesf[12][64];
    const int tid = threadIdx.x;
    const int r0 = blockIdx.x * RPB;
    const int m0 = blockIdx.y * 12;
    const int grow = r0 + tid;
    {
        const float4* xrp = (const float4*)x + (size_t)(grow < NROWS ? grow : NROWS - 1) * (NF / 4);
        float4 v[8];
        #pragma unroll
        for (int k = 0; k < 8; ++k) v[k] = xrp[k];
        #pragma unroll
        for (int k = 0; k < 8; ++k) {
            xsf[k*4+0][tid] = v[k].x; xsf[k*4+1][tid] = v[k].y;
            xsf[k*4+2][tid] = v[k].z; xsf[k*4+3][tid] = v[k].w;
        }
    }
    for (int i = tid; i < 12 * NINT; i += RPB) {
        int tl = i / NINT, nd = i - tl * NINT;
        int gi = (m0 + tl) * NINT + nd;
        nodesf[tl][nd] = make_int2(feat[gi], __float_as_int(thr[gi]));
    }
    __syncthreads();
    float acc0 = 0.f, acc1 = 0.f, acc2 = 0.f;
    for (int it = 0; it < 12; it += 6) {
        int idx[6] = {0,0,0,0,0,0};
        #pragma unroll
        for (int d = 0; d < 6; ++d) {
            #pragma unroll
            for (int j = 0; j < 6; ++j) {
                int2 nd = nodesf[it + j][idx[j]];
                idx[j] = 2*idx[j] + 1 + (int)(xsf[nd.x][tid] > __int_as_float(nd.y));
            }
        }
        #pragma unroll
        for (int j = 0; j < 6; ++j) {
            float lv = leaves[(m0 + it + j) * NLEAF + (idx[j] - NINT)];
            if (j % 3 == 0) acc0 += lv; else if (j % 3 == 1) acc1 += lv; else acc2 += lv;
        }
    }
    if (grow < NROWS) {
        atomicAdd(&out[grow*3+0], LRATE*acc0);
        atomicAdd(&out[grow*3+1], LRATE*acc1);
        atomicAdd(&out[grow*3+2], LRATE*acc2);
    }
}

extern "C" void kernel_launch(void* const* d_in, const int* in_sizes, int n_in,
                              void* d_out, int out_size, void* d_ws, size_t ws_size,
                              hipStream_t stream) {
    const float* x      = (const float*)d_in[0];
    const int*   feat   = (const int*)d_in[1];
    const float* thr    = (const float*)d_in[2];
    const float* leaves = (const float*)d_in[3];
    const float* initp  = (const float*)d_in[4];
    float* out = (float*)d_out;

    // ws layout:
    //   [0, 3200000)           xr u16[NF][NROWS]
    //   [3200000, 3331072)     sorted f32[NF][SORTN]
    //   [3331072, 3407872)     pack u32[NTREES][64]
    const size_t off_sorted = (size_t)NF * NROWS * 2;               // 3,200,000
    const size_t off_pack   = off_sorted + (size_t)NF * SORTN * 4;  // 3,331,072
    const size_t need       = off_pack + (size_t)NTREES * 64 * 4;   // 3,407,872

    if (ws_size >= need) {
        unsigned short* xrbuf  = (unsigned short*)d_ws;
        float*          sorted = (float*)((char*)d_ws + off_sorted);
        unsigned*       pack   = (unsigned*)((char*)d_ws + off_pack);

        dim3 g1(NF, SLICES);
        gb_prep<<<g1, 256, 0, stream>>>(feat, thr, sorted, pack);
        dim3 g2((NROWS + 255) / 256, NF);
        gb_rank_rows<<<g2, 256, 0, stream>>>(x, sorted, initp, xrbuf, out);
        dim3 g3((NROWS + RPB - 1) / RPB, TG);
        gb_forest<<<g3, RPB, 0, stream>>>(xrbuf, pack, leaves, out);
    } else {
        gb_init_out<<<(out_size + 255) / 256, 256, 0, stream>>>(initp, out, out_size);
        dim3 grid((NROWS + RPB - 1) / RPB, 25);
        gb_forest_fb<<<grid, RPB, 0, stream>>>(x, feat, thr, leaves, out);
    }
}